// Round 7
// baseline (92.540 us; speedup 1.0000x reference)
//
#include <hip/hip_runtime.h>
#include <hip/hip_bf16.h>

#define IMG_H 512
#define IMG_W 512
#define NBLOCKS 1536
#define TOTAL_ELEMS (48LL * 512 * 512)   // 16*3*512*512

#define PIN8(v) asm volatile("" :: "v"(v[0]), "v"(v[1]), "v"(v[2]), "v"(v[3]), \
                                   "v"(v[4]), "v"(v[5]), "v"(v[6]), "v"(v[7]))

__device__ __forceinline__ float fast_sqrtf(float x) {
    float r; asm("v_sqrt_f32 %0, %1" : "=v"(r) : "v"(x)); return r;   // ~1 ulp
}

__device__ __forceinline__ void load8(const float* __restrict__ p, float v[8]) {
    const float4 x = *reinterpret_cast<const float4*>(p);
    const float4 y = *reinterpret_cast<const float4*>(p + 4);
    v[0] = x.x; v[1] = x.y; v[2] = x.z; v[3] = x.w;
    v[4] = y.x; v[5] = y.y; v[6] = y.z; v[7] = y.w;
}

__device__ __forceinline__ void lds_read8(const float* s, float v[8]) {
    const float4 x = *reinterpret_cast<const float4*>(s);
    const float4 y = *reinterpret_cast<const float4*>(s + 4);
    v[0] = x.x; v[1] = x.y; v[2] = x.z; v[3] = x.w;
    v[4] = y.x; v[5] = y.y; v[6] = y.z; v[7] = y.w;
}

// Both images' Sobel magnitudes for one output row + |diff| partial sum.
// Column halo via shuffles on the linear vertical-pass terms (zero pad at edges).
__device__ __forceinline__ float row_absdiff(const float t1[8], const float m1[8], const float b1[8],
                                             const float t2[8], const float m2[8], const float b2[8],
                                             int lane) {
    float cs1[8], rd1[8], cs2[8], rd2[8];
#pragma unroll
    for (int j = 0; j < 8; ++j) {
        cs1[j] = (t1[j] + b1[j]) + 2.0f * m1[j];
        rd1[j] = b1[j] - t1[j];
        cs2[j] = (t2[j] + b2[j]) + 2.0f * m2[j];
        rd2[j] = b2[j] - t2[j];
    }
    float cs1L = __shfl_up(cs1[7], 1), cs1R = __shfl_down(cs1[0], 1);
    float rd1L = __shfl_up(rd1[7], 1), rd1R = __shfl_down(rd1[0], 1);
    float cs2L = __shfl_up(cs2[7], 1), cs2R = __shfl_down(cs2[0], 1);
    float rd2L = __shfl_up(rd2[7], 1), rd2R = __shfl_down(rd2[0], 1);
    if (lane == 0)  { cs1L = rd1L = cs2L = rd2L = 0.0f; }
    if (lane == 63) { cs1R = rd1R = cs2R = rd2R = 0.0f; }
    float s = 0.0f;
#pragma unroll
    for (int j = 0; j < 8; ++j) {
        const float ex1 = ((j == 7) ? cs1R : cs1[j + 1]) - ((j == 0) ? cs1L : cs1[j - 1]);
        const float ey1 = ((j == 0) ? rd1L : rd1[j - 1]) + 2.0f * rd1[j] + ((j == 7) ? rd1R : rd1[j + 1]);
        const float mg1 = fast_sqrtf(fmaf(ex1, ex1, fmaf(ey1, ey1, 1e-6f)));
        const float ex2 = ((j == 7) ? cs2R : cs2[j + 1]) - ((j == 0) ? cs2L : cs2[j - 1]);
        const float ey2 = ((j == 0) ? rd2L : rd2[j - 1]) + 2.0f * rd2[j] + ((j == 7) ? rd2R : rd2[j + 1]);
        const float mg2 = fast_sqrtf(fmaf(ex2, ex2, fmaf(ey2, ey2, 1e-6f)));
        s += fabsf(mg1 - mg2);
    }
    return s;
}

// R4 structure (best known: ~28-30 us kernel): halo rows in REGISTERS, LDS only
// publishes wave-boundary rows (32 KB). PIN8 keeps all loads issued up-front
// (prevents the R6 load-sinking low-VGPR schedule). Finalize fused via ticket.
__global__ __launch_bounds__(256) void edge_loss_kernel(const float* __restrict__ img1,
                                                        const float* __restrict__ img2,
                                                        float* __restrict__ slots,
                                                        unsigned* __restrict__ ticket,
                                                        float* __restrict__ out) {
    const int t = threadIdx.x;
    const int lane = t & 63;
    const int w = t >> 6;
    const int bid = blockIdx.x;
    const int swz = (bid & 7) * 192 + (bid >> 3);    // bijective XCD swizzle (1536=8*192)
    const int plane = swz >> 5;                      // 32 blocks per plane
    const int blk = swz & 31;
    const int yb = blk << 4;
    const int y0 = yb + (w << 2);
    const int x0 = lane << 3;
    const size_t base = (size_t)plane * (IMG_H * IMG_W);
    const float* p1 = img1 + base + x0;
    const float* p2 = img2 + base + x0;

    __shared__ float sh[2][4][2][IMG_W];             // 32 KB halo-exchange
    __shared__ float wave_sums[4];
    __shared__ bool amLast;

    float a[4][8], b[4][8];
#pragma unroll
    for (int r = 0; r < 4; ++r) {
        load8(p1 + (size_t)(y0 + r) * IMG_W, a[r]);
        load8(p2 + (size_t)(y0 + r) * IMG_W, b[r]);
    }

    float ha[8], hb[8];
    bool hzero = false;
    if (w == 0) {
        hzero = (yb == 0);
        const int y = hzero ? 0 : yb - 1;
        load8(p1 + (size_t)y * IMG_W, ha);
        load8(p2 + (size_t)y * IMG_W, hb);
    } else if (w == 3) {
        hzero = (yb + 16 == IMG_H);
        const int y = hzero ? IMG_H - 1 : yb + 16;
        load8(p1 + (size_t)y * IMG_W, ha);
        load8(p2 + (size_t)y * IMG_W, hb);
    }
    if (w == 0 || w == 3) {
        if (hzero) {
#pragma unroll
            for (int j = 0; j < 8; ++j) { ha[j] = 0.0f; hb[j] = 0.0f; }
        }
        PIN8(ha); PIN8(hb);                          // keep halo regs live here
    }
    // Pin all loaded rows: forces every global load above to have issued by now
    // (blocks the R6 "sink loads past the barrier" low-VGPR schedule).
    PIN8(a[0]); PIN8(a[1]); PIN8(a[2]); PIN8(a[3]);
    PIN8(b[0]); PIN8(b[1]); PIN8(b[2]); PIN8(b[3]);

    *reinterpret_cast<float4*>(&sh[0][w][0][x0])     = make_float4(a[0][0], a[0][1], a[0][2], a[0][3]);
    *reinterpret_cast<float4*>(&sh[0][w][0][x0 + 4]) = make_float4(a[0][4], a[0][5], a[0][6], a[0][7]);
    *reinterpret_cast<float4*>(&sh[0][w][1][x0])     = make_float4(a[3][0], a[3][1], a[3][2], a[3][3]);
    *reinterpret_cast<float4*>(&sh[0][w][1][x0 + 4]) = make_float4(a[3][4], a[3][5], a[3][6], a[3][7]);
    *reinterpret_cast<float4*>(&sh[1][w][0][x0])     = make_float4(b[0][0], b[0][1], b[0][2], b[0][3]);
    *reinterpret_cast<float4*>(&sh[1][w][0][x0 + 4]) = make_float4(b[0][4], b[0][5], b[0][6], b[0][7]);
    *reinterpret_cast<float4*>(&sh[1][w][1][x0])     = make_float4(b[3][0], b[3][1], b[3][2], b[3][3]);
    *reinterpret_cast<float4*>(&sh[1][w][1][x0 + 4]) = make_float4(b[3][4], b[3][5], b[3][6], b[3][7]);
    __syncthreads();

    float sum = 0.0f;
    {   // output row 0 (top halo JIT)
        float ta[8], tb[8];
        if (w == 0) {
#pragma unroll
            for (int j = 0; j < 8; ++j) { ta[j] = ha[j]; tb[j] = hb[j]; }
        } else {
            lds_read8(&sh[0][w - 1][1][x0], ta);
            lds_read8(&sh[1][w - 1][1][x0], tb);
        }
        sum += row_absdiff(ta, a[0], a[1], tb, b[0], b[1], lane);
    }
    sum += row_absdiff(a[0], a[1], a[2], b[0], b[1], b[2], lane);
    sum += row_absdiff(a[1], a[2], a[3], b[1], b[2], b[3], lane);
    {   // output row 3 (bottom halo JIT)
        float ba[8], bb[8];
        if (w == 3) {
#pragma unroll
            for (int j = 0; j < 8; ++j) { ba[j] = ha[j]; bb[j] = hb[j]; }
        } else {
            lds_read8(&sh[0][w + 1][0][x0], ba);
            lds_read8(&sh[1][w + 1][0][x0], bb);
        }
        sum += row_absdiff(a[2], a[3], ba, b[2], b[3], bb, lane);
    }

#pragma unroll
    for (int off = 32; off > 0; off >>= 1) sum += __shfl_down(sum, off);
    if (lane == 0) wave_sums[w] = sum;
    __syncthreads();

    if (t == 0) {
        const float s = (wave_sums[0] + wave_sums[1]) + (wave_sums[2] + wave_sums[3]);
        __hip_atomic_store(&slots[bid], s, __ATOMIC_RELEASE, __HIP_MEMORY_SCOPE_AGENT);
        const unsigned n = __hip_atomic_fetch_add(ticket, 1u, __ATOMIC_ACQ_REL,
                                                  __HIP_MEMORY_SCOPE_AGENT);
        amLast = (n == NBLOCKS - 1);
    }
    __syncthreads();                                  // amLast is block-uniform

    if (amLast) {                                     // unique last block finalizes
        float s = 0.0f;
#pragma unroll
        for (int i = 0; i < NBLOCKS / 256; ++i)       // fixed order -> deterministic
            s += __hip_atomic_load(&slots[t + i * 256], __ATOMIC_RELAXED, __HIP_MEMORY_SCOPE_AGENT);
#pragma unroll
        for (int off = 32; off > 0; off >>= 1) s += __shfl_down(s, off);
        if (lane == 0) wave_sums[w] = s;
        __syncthreads();
        if (t == 0) {
            out[0] = ((wave_sums[0] + wave_sums[1]) + (wave_sums[2] + wave_sums[3]))
                     * (1.0f / (float)TOTAL_ELEMS);
        }
    }
}

extern "C" void kernel_launch(void* const* d_in, const int* in_sizes, int n_in,
                              void* d_out, int out_size, void* d_ws, size_t ws_size,
                              hipStream_t stream) {
    const float* img1 = (const float*)d_in[0];
    const float* img2 = (const float*)d_in[1];
    float* out = (float*)d_out;
    unsigned* ticket = (unsigned*)d_ws;
    float* slots = (float*)((char*)d_ws + 256);

    hipMemsetAsync(ticket, 0, sizeof(unsigned), stream);
    edge_loss_kernel<<<dim3(NBLOCKS), 256, 0, stream>>>(img1, img2, slots, ticket, out);
}

// Round 8
// 28.067 us; speedup vs baseline: 3.2972x; 3.2972x over previous
//
#include <hip/hip_runtime.h>
#include <hip/hip_bf16.h>

#define IMG_H 512
#define IMG_W 512
#define NBLOCKS 1536
#define TOTAL_ELEMS (48LL * 512 * 512)   // 16*3*512*512

__device__ __forceinline__ float fast_sqrtf(float x) {
    float r; asm("v_sqrt_f32 %0, %1" : "=v"(r) : "v"(x)); return r;   // ~1 ulp
}

__device__ __forceinline__ void load8(const float* __restrict__ p, float v[8]) {
    const float4 x = *reinterpret_cast<const float4*>(p);
    const float4 y = *reinterpret_cast<const float4*>(p + 4);
    v[0] = x.x; v[1] = x.y; v[2] = x.z; v[3] = x.w;
    v[4] = y.x; v[5] = y.y; v[6] = y.z; v[7] = y.w;
}

__device__ __forceinline__ void lds_read8(const float* __restrict__ s, float v[8]) {
    const float4 x = *reinterpret_cast<const float4*>(s);
    const float4 y = *reinterpret_cast<const float4*>(s + 4);
    v[0] = x.x; v[1] = x.y; v[2] = x.z; v[3] = x.w;
    v[4] = y.x; v[5] = y.y; v[6] = y.z; v[7] = y.w;
}

// Separable Sobel magnitude for one output row (8 px/lane); column halo via
// 2 shuffles on the linear vertical-pass terms (zero pad at image edges).
__device__ __forceinline__ void sobel_mag_row(const float t[8], const float m[8], const float b[8],
                                              int lane, float mag[8]) {
    float cs[8], rd[8];
#pragma unroll
    for (int j = 0; j < 8; ++j) {
        cs[j] = (t[j] + b[j]) + 2.0f * m[j];   // vertical [1,2,1]
        rd[j] = b[j] - t[j];                   // vertical [-1,0,1]
    }
    float csL = __shfl_up(cs[7], 1), csR = __shfl_down(cs[0], 1);
    float rdL = __shfl_up(rd[7], 1), rdR = __shfl_down(rd[0], 1);
    if (lane == 0)  { csL = 0.0f; rdL = 0.0f; }
    if (lane == 63) { csR = 0.0f; rdR = 0.0f; }
#pragma unroll
    for (int j = 0; j < 8; ++j) {
        const float ex = ((j == 7) ? csR : cs[j + 1]) - ((j == 0) ? csL : cs[j - 1]);
        const float ey = ((j == 0) ? rdL : rd[j - 1]) + 2.0f * rd[j] + ((j == 7) ? rdR : rd[j + 1]);
        mag[j] = fast_sqrtf(fmaf(ex, ex, fmaf(ey, ey, 1e-6f)));
    }
}

// R4 structure verbatim (known-good ~28 us schedule). Block = 4 waves =
// 16-row x 512-col tile; each wave loads only its 4 rows (+1 global halo row
// for waves 0/3); wave-boundary rows via LDS (1.125x reads). Tail: plain
// per-block slot store (no atomic, no memset needed).
__global__ __launch_bounds__(256) void edge_loss_kernel(const float* __restrict__ img1,
                                                        const float* __restrict__ img2,
                                                        float* __restrict__ slots) {
    const int t = threadIdx.x;
    const int lane = t & 63;
    const int w = t >> 6;
    const int bid = blockIdx.x;
    const int swz = (bid & 7) * 192 + (bid >> 3);   // bijective XCD swizzle
    const int plane = swz >> 5;                     // 32 blocks per plane
    const int blk = swz & 31;
    const int yb = blk << 4;                        // tile top row
    const int y0 = yb + (w << 2);                   // this wave's first row
    const int x0 = lane << 3;
    const size_t base = (size_t)plane * (IMG_H * IMG_W);
    const float* p1 = img1 + base + x0;
    const float* p2 = img2 + base + x0;

    __shared__ float sh[2][4][2][IMG_W];            // 32 KB halo-exchange

    float a[4][8], b[4][8];
#pragma unroll
    for (int r = 0; r < 4; ++r) {
        load8(p1 + (size_t)(y0 + r) * IMG_W, a[r]);
        load8(p2 + (size_t)(y0 + r) * IMG_W, b[r]);
    }

    float ha[8], hb[8];
    bool hzero = false;
    if (w == 0) {
        hzero = (yb == 0);
        const int y = hzero ? 0 : yb - 1;
        load8(p1 + (size_t)y * IMG_W, ha);
        load8(p2 + (size_t)y * IMG_W, hb);
    } else if (w == 3) {
        hzero = (yb + 16 == IMG_H);
        const int y = hzero ? IMG_H - 1 : yb + 16;
        load8(p1 + (size_t)y * IMG_W, ha);
        load8(p2 + (size_t)y * IMG_W, hb);
    }
    if ((w == 0 || w == 3) && hzero) {
#pragma unroll
        for (int j = 0; j < 8; ++j) { ha[j] = 0.0f; hb[j] = 0.0f; }
    }

    *reinterpret_cast<float4*>(&sh[0][w][0][x0])     = make_float4(a[0][0], a[0][1], a[0][2], a[0][3]);
    *reinterpret_cast<float4*>(&sh[0][w][0][x0 + 4]) = make_float4(a[0][4], a[0][5], a[0][6], a[0][7]);
    *reinterpret_cast<float4*>(&sh[0][w][1][x0])     = make_float4(a[3][0], a[3][1], a[3][2], a[3][3]);
    *reinterpret_cast<float4*>(&sh[0][w][1][x0 + 4]) = make_float4(a[3][4], a[3][5], a[3][6], a[3][7]);
    *reinterpret_cast<float4*>(&sh[1][w][0][x0])     = make_float4(b[0][0], b[0][1], b[0][2], b[0][3]);
    *reinterpret_cast<float4*>(&sh[1][w][0][x0 + 4]) = make_float4(b[0][4], b[0][5], b[0][6], b[0][7]);
    *reinterpret_cast<float4*>(&sh[1][w][1][x0])     = make_float4(b[3][0], b[3][1], b[3][2], b[3][3]);
    *reinterpret_cast<float4*>(&sh[1][w][1][x0 + 4]) = make_float4(b[3][4], b[3][5], b[3][6], b[3][7]);
    __syncthreads();

    // assemble halo rows: top = row y0-1, bot = row y0+4 (per image)
    float ta[8], tb[8], ba[8], bb[8];
    if (w == 0) {
#pragma unroll
        for (int j = 0; j < 8; ++j) { ta[j] = ha[j]; tb[j] = hb[j]; }
    } else {
        lds_read8(&sh[0][w - 1][1][x0], ta);
        lds_read8(&sh[1][w - 1][1][x0], tb);
    }
    if (w == 3) {
#pragma unroll
        for (int j = 0; j < 8; ++j) { ba[j] = ha[j]; bb[j] = hb[j]; }
    } else {
        lds_read8(&sh[0][w + 1][0][x0], ba);
        lds_read8(&sh[1][w + 1][0][x0], bb);
    }

    // image 1 magnitudes, then image 2 + abs-diff accumulate
    float m1[4][8];
    sobel_mag_row(ta,   a[0], a[1], lane, m1[0]);
    sobel_mag_row(a[0], a[1], a[2], lane, m1[1]);
    sobel_mag_row(a[1], a[2], a[3], lane, m1[2]);
    sobel_mag_row(a[2], a[3], ba,   lane, m1[3]);

    float sum = 0.0f;
    {
        float m2[8];
        sobel_mag_row(tb,   b[0], b[1], lane, m2);
#pragma unroll
        for (int j = 0; j < 8; ++j) sum += fabsf(m1[0][j] - m2[j]);
        sobel_mag_row(b[0], b[1], b[2], lane, m2);
#pragma unroll
        for (int j = 0; j < 8; ++j) sum += fabsf(m1[1][j] - m2[j]);
        sobel_mag_row(b[1], b[2], b[3], lane, m2);
#pragma unroll
        for (int j = 0; j < 8; ++j) sum += fabsf(m1[2][j] - m2[j]);
        sobel_mag_row(b[2], b[3], bb,   lane, m2);
#pragma unroll
        for (int j = 0; j < 8; ++j) sum += fabsf(m1[3][j] - m2[j]);
    }

#pragma unroll
    for (int off = 32; off > 0; off >>= 1) sum += __shfl_down(sum, off);

    __shared__ float wave_sums[4];
    if (lane == 0) wave_sums[w] = sum;
    __syncthreads();
    if (t == 0) {
        slots[bid] = (wave_sums[0] + wave_sums[1]) + (wave_sums[2] + wave_sums[3]);
    }
}

// Deterministic fixed-order reduction of the 1536 per-block partials.
__global__ __launch_bounds__(256) void finalize_kernel(const float* __restrict__ slots,
                                                       float* __restrict__ out) {
    const int t = threadIdx.x;
    const int lane = t & 63;
    const int w = t >> 6;
    float s = 0.0f;
#pragma unroll
    for (int i = 0; i < NBLOCKS / 256; ++i) s += slots[t + i * 256];
#pragma unroll
    for (int off = 32; off > 0; off >>= 1) s += __shfl_down(s, off);
    __shared__ float ws[4];
    if (lane == 0) ws[w] = s;
    __syncthreads();
    if (t == 0) out[0] = ((ws[0] + ws[1]) + (ws[2] + ws[3])) * (1.0f / (float)TOTAL_ELEMS);
}

extern "C" void kernel_launch(void* const* d_in, const int* in_sizes, int n_in,
                              void* d_out, int out_size, void* d_ws, size_t ws_size,
                              hipStream_t stream) {
    const float* img1 = (const float*)d_in[0];
    const float* img2 = (const float*)d_in[1];
    float* out = (float*)d_out;
    float* slots = (float*)d_ws;    // 1536 floats, fully rewritten every call

    edge_loss_kernel<<<dim3(NBLOCKS), 256, 0, stream>>>(img1, img2, slots);
    finalize_kernel<<<dim3(1), 256, 0, stream>>>(slots, out);
}

// Round 9
// 24.294 us; speedup vs baseline: 3.8092x; 1.1553x over previous
//
#include <hip/hip_runtime.h>
#include <hip/hip_bf16.h>

#define IMG_H 512
#define IMG_W 512
#define NBLOCKS 768
#define TOTAL_ELEMS (48LL * 512 * 512)   // 16*3*512*512

__device__ __forceinline__ float fast_sqrtf(float x) {
    float r; asm("v_sqrt_f32 %0, %1" : "=v"(r) : "v"(x)); return r;   // ~1 ulp
}

__device__ __forceinline__ void load8(const float* __restrict__ p, float v[8]) {
    const float4 x = *reinterpret_cast<const float4*>(p);
    const float4 y = *reinterpret_cast<const float4*>(p + 4);
    v[0] = x.x; v[1] = x.y; v[2] = x.z; v[3] = x.w;
    v[4] = y.x; v[5] = y.y; v[6] = y.z; v[7] = y.w;
}

__device__ __forceinline__ void lds_read8(const float* __restrict__ s, float v[8]) {
    const float4 x = *reinterpret_cast<const float4*>(s);
    const float4 y = *reinterpret_cast<const float4*>(s + 4);
    v[0] = x.x; v[1] = x.y; v[2] = x.z; v[3] = x.w;
    v[4] = y.x; v[5] = y.y; v[6] = y.z; v[7] = y.w;
}

// Separable Sobel magnitude for one output row (8 px/lane); column halo via
// 2 shuffles on the linear vertical-pass terms (zero pad at image edges).
__device__ __forceinline__ void sobel_mag_row(const float t[8], const float m[8], const float b[8],
                                              int lane, float mag[8]) {
    float cs[8], rd[8];
#pragma unroll
    for (int j = 0; j < 8; ++j) {
        cs[j] = (t[j] + b[j]) + 2.0f * m[j];   // vertical [1,2,1]
        rd[j] = b[j] - t[j];                   // vertical [-1,0,1]
    }
    float csL = __shfl_up(cs[7], 1), csR = __shfl_down(cs[0], 1);
    float rdL = __shfl_up(rd[7], 1), rdR = __shfl_down(rd[0], 1);
    if (lane == 0)  { csL = 0.0f; rdL = 0.0f; }
    if (lane == 63) { csR = 0.0f; rdR = 0.0f; }
#pragma unroll
    for (int j = 0; j < 8; ++j) {
        const float ex = ((j == 7) ? csR : cs[j + 1]) - ((j == 0) ? csL : cs[j - 1]);
        const float ey = ((j == 0) ? rdL : rd[j - 1]) + 2.0f * rd[j] + ((j == 7) ? rdR : rd[j + 1]);
        mag[j] = fast_sqrtf(fmaf(ex, ex, fmaf(ey, ey, 1e-6f)));
    }
}

// R8 per-wave code verbatim; tile doubled to 32 rows (8 waves x 4 rows, 512
// threads) -> halo amplification 34/32 = 1.0625x (was 1.125x). LDS 64 KB ->
// 2 blocks/CU = 16 waves/CU (unchanged). Grid 768 = 8 XCDs * 96, swizzled.
__global__ __launch_bounds__(512) void edge_loss_kernel(const float* __restrict__ img1,
                                                        const float* __restrict__ img2,
                                                        float* __restrict__ slots) {
    const int t = threadIdx.x;
    const int lane = t & 63;
    const int w = t >> 6;                           // 0..7
    const int bid = blockIdx.x;
    const int swz = (bid & 7) * 96 + (bid >> 3);    // bijective XCD swizzle (768=8*96)
    const int plane = swz >> 4;                     // 16 blocks per plane
    const int blk = swz & 15;
    const int yb = blk << 5;                        // tile top row (32-row tile)
    const int y0 = yb + (w << 2);                   // this wave's first row
    const int x0 = lane << 3;
    const size_t base = (size_t)plane * (IMG_H * IMG_W);
    const float* p1 = img1 + base + x0;
    const float* p2 = img2 + base + x0;

    __shared__ float sh[2][8][2][IMG_W];            // 64 KB halo-exchange
    __shared__ float wave_sums[8];

    float a[4][8], b[4][8];
#pragma unroll
    for (int r = 0; r < 4; ++r) {
        load8(p1 + (size_t)(y0 + r) * IMG_W, a[r]);
        load8(p2 + (size_t)(y0 + r) * IMG_W, b[r]);
    }

    float ha[8], hb[8];
    bool hzero = false;
    if (w == 0) {
        hzero = (yb == 0);
        const int y = hzero ? 0 : yb - 1;
        load8(p1 + (size_t)y * IMG_W, ha);
        load8(p2 + (size_t)y * IMG_W, hb);
    } else if (w == 7) {
        hzero = (yb + 32 == IMG_H);
        const int y = hzero ? IMG_H - 1 : yb + 32;
        load8(p1 + (size_t)y * IMG_W, ha);
        load8(p2 + (size_t)y * IMG_W, hb);
    }
    if ((w == 0 || w == 7) && hzero) {
#pragma unroll
        for (int j = 0; j < 8; ++j) { ha[j] = 0.0f; hb[j] = 0.0f; }
    }

    *reinterpret_cast<float4*>(&sh[0][w][0][x0])     = make_float4(a[0][0], a[0][1], a[0][2], a[0][3]);
    *reinterpret_cast<float4*>(&sh[0][w][0][x0 + 4]) = make_float4(a[0][4], a[0][5], a[0][6], a[0][7]);
    *reinterpret_cast<float4*>(&sh[0][w][1][x0])     = make_float4(a[3][0], a[3][1], a[3][2], a[3][3]);
    *reinterpret_cast<float4*>(&sh[0][w][1][x0 + 4]) = make_float4(a[3][4], a[3][5], a[3][6], a[3][7]);
    *reinterpret_cast<float4*>(&sh[1][w][0][x0])     = make_float4(b[0][0], b[0][1], b[0][2], b[0][3]);
    *reinterpret_cast<float4*>(&sh[1][w][0][x0 + 4]) = make_float4(b[0][4], b[0][5], b[0][6], b[0][7]);
    *reinterpret_cast<float4*>(&sh[1][w][1][x0])     = make_float4(b[3][0], b[3][1], b[3][2], b[3][3]);
    *reinterpret_cast<float4*>(&sh[1][w][1][x0 + 4]) = make_float4(b[3][4], b[3][5], b[3][6], b[3][7]);
    __syncthreads();

    // assemble halo rows: top = row y0-1, bot = row y0+4 (per image)
    float ta[8], tb[8], ba[8], bb[8];
    if (w == 0) {
#pragma unroll
        for (int j = 0; j < 8; ++j) { ta[j] = ha[j]; tb[j] = hb[j]; }
    } else {
        lds_read8(&sh[0][w - 1][1][x0], ta);
        lds_read8(&sh[1][w - 1][1][x0], tb);
    }
    if (w == 7) {
#pragma unroll
        for (int j = 0; j < 8; ++j) { ba[j] = ha[j]; bb[j] = hb[j]; }
    } else {
        lds_read8(&sh[0][w + 1][0][x0], ba);
        lds_read8(&sh[1][w + 1][0][x0], bb);
    }

    // image 1 magnitudes, then image 2 + abs-diff accumulate
    float m1[4][8];
    sobel_mag_row(ta,   a[0], a[1], lane, m1[0]);
    sobel_mag_row(a[0], a[1], a[2], lane, m1[1]);
    sobel_mag_row(a[1], a[2], a[3], lane, m1[2]);
    sobel_mag_row(a[2], a[3], ba,   lane, m1[3]);

    float sum = 0.0f;
    {
        float m2[8];
        sobel_mag_row(tb,   b[0], b[1], lane, m2);
#pragma unroll
        for (int j = 0; j < 8; ++j) sum += fabsf(m1[0][j] - m2[j]);
        sobel_mag_row(b[0], b[1], b[2], lane, m2);
#pragma unroll
        for (int j = 0; j < 8; ++j) sum += fabsf(m1[1][j] - m2[j]);
        sobel_mag_row(b[1], b[2], b[3], lane, m2);
#pragma unroll
        for (int j = 0; j < 8; ++j) sum += fabsf(m1[2][j] - m2[j]);
        sobel_mag_row(b[2], b[3], bb,   lane, m2);
#pragma unroll
        for (int j = 0; j < 8; ++j) sum += fabsf(m1[3][j] - m2[j]);
    }

#pragma unroll
    for (int off = 32; off > 0; off >>= 1) sum += __shfl_down(sum, off);

    if (lane == 0) wave_sums[w] = sum;
    __syncthreads();
    if (t == 0) {
        float s = 0.0f;
#pragma unroll
        for (int i = 0; i < 8; ++i) s += wave_sums[i];
        slots[bid] = s;
    }
}

// Deterministic fixed-order reduction of the 768 per-block partials.
__global__ __launch_bounds__(256) void finalize_kernel(const float* __restrict__ slots,
                                                       float* __restrict__ out) {
    const int t = threadIdx.x;
    const int lane = t & 63;
    const int w = t >> 6;
    float s = 0.0f;
#pragma unroll
    for (int i = 0; i < NBLOCKS / 256; ++i) s += slots[t + i * 256];
#pragma unroll
    for (int off = 32; off > 0; off >>= 1) s += __shfl_down(s, off);
    __shared__ float ws[4];
    if (lane == 0) ws[w] = s;
    __syncthreads();
    if (t == 0) out[0] = ((ws[0] + ws[1]) + (ws[2] + ws[3])) * (1.0f / (float)TOTAL_ELEMS);
}

extern "C" void kernel_launch(void* const* d_in, const int* in_sizes, int n_in,
                              void* d_out, int out_size, void* d_ws, size_t ws_size,
                              hipStream_t stream) {
    const float* img1 = (const float*)d_in[0];
    const float* img2 = (const float*)d_in[1];
    float* out = (float*)d_out;
    float* slots = (float*)d_ws;    // 768 floats, fully rewritten every call

    edge_loss_kernel<<<dim3(NBLOCKS), 512, 0, stream>>>(img1, img2, slots);
    finalize_kernel<<<dim3(1), 256, 0, stream>>>(slots, out);
}